// Round 1
// baseline (1127.166 us; speedup 1.0000x reference)
//
#include <hip/hip_runtime.h>
#include <cmath>

// LinearGaussianChain: chunked parallel scan over the 255-step affine recurrence.
// Chunks: 16 chunks x 16 steps. Phase1: per-chunk zero-start chains (v_c).
// k_prod: per-chunk transfer matrices M_c (bf16 MFMA). Phase2: sequential
// boundary stitch. Phase3: per-chunk recompute from true boundary + staged,
// coalesced output writes (x, m, s) in (M, NODE, T-flipped) layout.

typedef __bf16 bf16x8 __attribute__((ext_vector_type(8)));
typedef float f32x4 __attribute__((ext_vector_type(4)));

#define XB_STRIDE 144  // bytes per LDS row: 64 bf16 (128B) + 16B pad (16B-aligned rows)

__device__ __forceinline__ float softplus_f(float z) {
  return (z > 20.0f) ? z : log1pf(expf(z));
}

// ---- K0a: repack W (T,64,64) fp32 -> bf16 B-fragment order ----
// Wf entry: ((t*4 + nt)*2 + kh)*64 + lane, lane=(q<<4)|n15 holds
// W[t][16*nt + n15][32*kh + 8*q + j], j=0..7  (B[k][n] = W[n][k] for x @ W^T)
__global__ void k_wf(const float* __restrict__ W, bf16x8* __restrict__ Wf) {
  int t = blockIdx.x;
  for (int e = threadIdx.x; e < 512; e += blockDim.x) {
    int lane = e & 63;
    int kh = (e >> 6) & 1;
    int nt = e >> 7;
    int q = lane >> 4, n15 = lane & 15;
    int n = nt * 16 + n15;
    int k0 = kh * 32 + q * 8;
    const float* src = W + ((size_t)t * 64 + n) * 64 + k0;
    bf16x8 v;
#pragma unroll
    for (int j = 0; j < 8; ++j) v[j] = (__bf16)src[j];
    Wf[((size_t)(t * 4 + nt) * 2 + kh) * 64 + lane] = v;
  }
}

// ---- K0b: per-chunk transfer matrix products M_c, stored as B-frags ----
// Track Q = M_c^T as 64 "batch rows": Q <- Q @ W_t^T each step. 4 waves/block.
__global__ __launch_bounds__(256, 2) void k_prod(const bf16x8* __restrict__ Wf,
                                                 bf16x8* __restrict__ Mcf) {
  __shared__ __align__(16) unsigned char Q[64 * XB_STRIDE];
  int c = blockIdx.x;
  int tid = threadIdx.x;
  int lane = tid & 63, w = tid >> 6;
  int q = lane >> 4, n15 = lane & 15;
  int rbase = w * 16;
  for (int e = tid; e < 64 * 64; e += 256) {
    int r = e >> 6, k = e & 63;
    *(__bf16*)(Q + r * XB_STRIDE + k * 2) = (__bf16)((r == k) ? 1.0f : 0.0f);
  }
  __syncthreads();
  int t0 = (c == 0) ? 1 : c * 16;
  int t1 = c * 16 + 16;
  for (int t = t0; t < t1; ++t) {
    bf16x8 a0 = *(const bf16x8*)(Q + (rbase + n15) * XB_STRIDE + q * 16);
    bf16x8 a1 = *(const bf16x8*)(Q + (rbase + n15) * XB_STRIDE + 64 + q * 16);
    f32x4 acc[4];
#pragma unroll
    for (int nt = 0; nt < 4; ++nt) {
      bf16x8 b0 = Wf[((size_t)(t * 4 + nt) * 2 + 0) * 64 + lane];
      bf16x8 b1 = Wf[((size_t)(t * 4 + nt) * 2 + 1) * 64 + lane];
      f32x4 z = {0.f, 0.f, 0.f, 0.f};
      z = __builtin_amdgcn_mfma_f32_16x16x32_bf16(a0, b0, z, 0, 0, 0);
      z = __builtin_amdgcn_mfma_f32_16x16x32_bf16(a1, b1, z, 0, 0, 0);
      acc[nt] = z;
    }
    __syncthreads();
#pragma unroll
    for (int nt = 0; nt < 4; ++nt) {
#pragma unroll
      for (int reg = 0; reg < 4; ++reg) {
        int row = rbase + 4 * q + reg;
        int col = nt * 16 + n15;
        *(__bf16*)(Q + row * XB_STRIDE + col * 2) = (__bf16)acc[nt][reg];
      }
    }
    __syncthreads();
  }
  // Mc[n][k] = Q[k][n]; emit B-frag order for phase 2.
  for (int e = tid; e < 512; e += 256) {
    int lane2 = e & 63;
    int kh = (e >> 6) & 1;
    int nt = e >> 7;
    int q2 = lane2 >> 4;
    int nn = nt * 16 + (lane2 & 15);
    bf16x8 v;
#pragma unroll
    for (int j = 0; j < 8; ++j) {
      int k = kh * 32 + q2 * 8 + j;
      v[j] = *(const __bf16*)(Q + k * XB_STRIDE + nn * 2);
    }
    Mcf[((size_t)c * 8 + nt * 2 + kh) * 64 + lane2] = v;
  }
}

// ---- K1 (phase 1): zero-start chunk chains -> v_c ----
__global__ __launch_bounds__(64, 4) void k_phase1(
    const float* __restrict__ bb, const float* __restrict__ ne,
    const float* __restrict__ eps, const bf16x8* __restrict__ Wf,
    float* __restrict__ vout) {
  __shared__ __align__(16) unsigned char xb[16 * XB_STRIDE];
  __shared__ float stab[16][64];
  __shared__ float btab[16][64];
  int bid = blockIdx.x;
  int c = bid >> 7;          // 0..14
  int r0 = (bid & 127) * 16; // row tile
  int lane = threadIdx.x;
  int q = lane >> 4, n15 = lane & 15;
  for (int e = lane; e < 1024; e += 64) {
    int tl = e >> 6, n = e & 63;
    int t = c * 16 + tl;
    stab[tl][n] = softplus_f(ne[n * 256 + t]);
    btab[tl][n] = bb[t * 64 + n];
  }
  for (int e = lane; e < 16 * (XB_STRIDE / 2); e += 64)
    ((__bf16*)xb)[e] = (__bf16)0.0f;
  __syncthreads();
  float xv[16];
  int t0 = (c == 0) ? 1 : c * 16;
  for (int t = t0; t < c * 16 + 16; ++t) {
    int tl = t - c * 16;
    bf16x8 a0 = *(const bf16x8*)(xb + n15 * XB_STRIDE + q * 16);
    bf16x8 a1 = *(const bf16x8*)(xb + n15 * XB_STRIDE + 64 + q * 16);
    f32x4 acc[4];
#pragma unroll
    for (int nt = 0; nt < 4; ++nt) {
      bf16x8 b0 = Wf[((size_t)(t * 4 + nt) * 2 + 0) * 64 + lane];
      bf16x8 b1 = Wf[((size_t)(t * 4 + nt) * 2 + 1) * 64 + lane];
      f32x4 z = {0.f, 0.f, 0.f, 0.f};
      z = __builtin_amdgcn_mfma_f32_16x16x32_bf16(a0, b0, z, 0, 0, 0);
      z = __builtin_amdgcn_mfma_f32_16x16x32_bf16(a1, b1, z, 0, 0, 0);
      acc[nt] = z;
    }
    __syncthreads();
#pragma unroll
    for (int nt = 0; nt < 4; ++nt) {
      int n = nt * 16 + n15;
      float sv = stab[tl][n];
      float bv = btab[tl][n];
#pragma unroll
      for (int reg = 0; reg < 4; ++reg) {
        int row = 4 * q + reg;
        int mrow = r0 + row;
        float e = eps[((size_t)(t - 1) * 2048 + mrow) * 64 + n];
        float xn = acc[nt][reg] + bv + sv * e;
        xv[nt * 4 + reg] = xn;
        *(__bf16*)(xb + row * XB_STRIDE + n * 2) = (__bf16)xn;
      }
    }
    __syncthreads();
  }
#pragma unroll
  for (int nt = 0; nt < 4; ++nt)
#pragma unroll
    for (int reg = 0; reg < 4; ++reg)
      vout[((size_t)c * 2048 + r0 + 4 * q + reg) * 64 + nt * 16 + n15] =
          xv[nt * 4 + reg];
}

// ---- K2 (phase 2): sequential boundary stitch over 15 chunk transitions ----
__global__ __launch_bounds__(64, 4) void k_phase2(
    const float* __restrict__ eps0, const bf16x8* __restrict__ Mcf,
    const float* __restrict__ vin, float* __restrict__ bnd) {
  __shared__ __align__(16) unsigned char xb[16 * XB_STRIDE];
  int r0 = blockIdx.x * 16;
  int lane = threadIdx.x;
  int q = lane >> 4, n15 = lane & 15;
  for (int e = lane; e < 1024; e += 64) {
    int r = e >> 6, k = e & 63;
    *(__bf16*)(xb + r * XB_STRIDE + k * 2) =
        (__bf16)eps0[(size_t)(r0 + r) * 64 + k];  // x_0 = eps0 (IN_SCALE=1)
  }
  __syncthreads();
  for (int c = 0; c < 15; ++c) {
    bf16x8 a0 = *(const bf16x8*)(xb + n15 * XB_STRIDE + q * 16);
    bf16x8 a1 = *(const bf16x8*)(xb + n15 * XB_STRIDE + 64 + q * 16);
    f32x4 acc[4];
#pragma unroll
    for (int nt = 0; nt < 4; ++nt) {
      bf16x8 b0 = Mcf[((size_t)c * 8 + nt * 2 + 0) * 64 + lane];
      bf16x8 b1 = Mcf[((size_t)c * 8 + nt * 2 + 1) * 64 + lane];
      f32x4 z = {0.f, 0.f, 0.f, 0.f};
      z = __builtin_amdgcn_mfma_f32_16x16x32_bf16(a0, b0, z, 0, 0, 0);
      z = __builtin_amdgcn_mfma_f32_16x16x32_bf16(a1, b1, z, 0, 0, 0);
      acc[nt] = z;
    }
    __syncthreads();
#pragma unroll
    for (int nt = 0; nt < 4; ++nt) {
      int n = nt * 16 + n15;
#pragma unroll
      for (int reg = 0; reg < 4; ++reg) {
        int row = 4 * q + reg;
        int mrow = r0 + row;
        float xn = acc[nt][reg] + vin[((size_t)c * 2048 + mrow) * 64 + n];
        bnd[((size_t)(c + 1) * 2048 + mrow) * 64 + n] = xn;
        *(__bf16*)(xb + row * XB_STRIDE + n * 2) = (__bf16)xn;
      }
    }
    __syncthreads();
  }
}

// ---- K3 (phase 3): recompute from true boundary, staged coalesced writes ----
__global__ __launch_bounds__(64, 2) void k_phase3(
    const float* __restrict__ bb, const float* __restrict__ ne,
    const float* __restrict__ eps0, const float* __restrict__ eps,
    const bf16x8* __restrict__ Wf, const float* __restrict__ bnd,
    float* __restrict__ out) {
  __shared__ __align__(16) unsigned char xb[16 * XB_STRIDE];
  __shared__ float stab[16][64];
  __shared__ float btab[16][64];
  int bid = blockIdx.x;
  int c = bid >> 7;
  int r0 = (bid & 127) * 16;
  int lane = threadIdx.x;
  int q = lane >> 4, n15 = lane & 15;
  for (int e = lane; e < 1024; e += 64) {
    int tl = e >> 6, n = e & 63;
    int t = c * 16 + tl;
    float sc = softplus_f(ne[n * 256 + t]);
    if (c == 0 && tl == 0) sc = 1.0f;  // s_0 = IN_SCALE
    stab[tl][n] = sc;
    btab[tl][n] = bb[t * 64 + n];
  }
  if (c > 0) {
    for (int e = lane; e < 1024; e += 64) {
      int r = e >> 6, k = e & 63;
      *(__bf16*)(xb + r * XB_STRIDE + k * 2) =
          (__bf16)bnd[((size_t)c * 2048 + r0 + r) * 64 + k];
    }
  }
  __syncthreads();
  float stg[8][16];
  const size_t MSOFF = (size_t)2048 * 64 * 256;
  for (int g = 0; g < 2; ++g) {
#pragma unroll
    for (int s = 0; s < 8; ++s) {
      int tl = g * 8 + s;
      int t = c * 16 + tl;
      if (c == 0 && tl == 0) {
        // x_0 = eps0, loaded straight into D-layout staging + LDS state.
#pragma unroll
        for (int nt = 0; nt < 4; ++nt) {
          int n = nt * 16 + n15;
#pragma unroll
          for (int reg = 0; reg < 4; ++reg) {
            int row = 4 * q + reg;
            float e = eps0[(size_t)(r0 + row) * 64 + n];
            stg[0][nt * 4 + reg] = e;
            *(__bf16*)(xb + row * XB_STRIDE + n * 2) = (__bf16)e;
          }
        }
        __syncthreads();
        continue;
      }
      bf16x8 a0 = *(const bf16x8*)(xb + n15 * XB_STRIDE + q * 16);
      bf16x8 a1 = *(const bf16x8*)(xb + n15 * XB_STRIDE + 64 + q * 16);
      f32x4 acc[4];
#pragma unroll
      for (int nt = 0; nt < 4; ++nt) {
        bf16x8 b0 = Wf[((size_t)(t * 4 + nt) * 2 + 0) * 64 + lane];
        bf16x8 b1 = Wf[((size_t)(t * 4 + nt) * 2 + 1) * 64 + lane];
        f32x4 z = {0.f, 0.f, 0.f, 0.f};
        z = __builtin_amdgcn_mfma_f32_16x16x32_bf16(a0, b0, z, 0, 0, 0);
        z = __builtin_amdgcn_mfma_f32_16x16x32_bf16(a1, b1, z, 0, 0, 0);
        acc[nt] = z;
      }
      __syncthreads();
#pragma unroll
      for (int nt = 0; nt < 4; ++nt) {
        int n = nt * 16 + n15;
        float sv = stab[tl][n];
        float bv = btab[tl][n];
#pragma unroll
        for (int reg = 0; reg < 4; ++reg) {
          int row = 4 * q + reg;
          int mrow = r0 + row;
          float e = eps[((size_t)(t - 1) * 2048 + mrow) * 64 + n];
          float xn = acc[nt][reg] + bv + sv * e;
          stg[s][nt * 4 + reg] = xn;
          *(__bf16*)(xb + row * XB_STRIDE + n * 2) = (__bf16)xn;
        }
      }
      __syncthreads();
    }
    // flush group g: 8 t-steps -> 32B contiguous segments per (m,n)
    int tbase = c * 16 + g * 8;
    int i0 = 248 - tbase;  // = 255 - tbase - 7, 8-aligned
#pragma unroll
    for (int nt = 0; nt < 4; ++nt) {
      int n = nt * 16 + n15;
#pragma unroll
      for (int reg = 0; reg < 4; ++reg) {
        int mrow = r0 + 4 * q + reg;
        size_t base = ((size_t)mrow * 64 + n) * 256 + i0;
        float xv[8], mv[8], sv[8];
#pragma unroll
        for (int s = 0; s < 8; ++s) {
          int t = tbase + s;
          int tl = t - c * 16;
          float e = (t == 0) ? eps0[(size_t)mrow * 64 + n]
                             : eps[((size_t)(t - 1) * 2048 + mrow) * 64 + n];
          float sc = stab[tl][n];
          xv[s] = stg[s][nt * 4 + reg];
          mv[s] = xv[s] - sc * e;  // m_t = x_t - s_t*eps_t (exact incl. t=0)
          sv[s] = sc;
        }
        f32x4 wx0 = {xv[7], xv[6], xv[5], xv[4]};
        f32x4 wx1 = {xv[3], xv[2], xv[1], xv[0]};
        *(f32x4*)(out + base) = wx0;
        *(f32x4*)(out + base + 4) = wx1;
        f32x4 wm0 = {mv[7], mv[6], mv[5], mv[4]};
        f32x4 wm1 = {mv[3], mv[2], mv[1], mv[0]};
        *(f32x4*)(out + MSOFF + base) = wm0;
        *(f32x4*)(out + MSOFF + base + 4) = wm1;
        f32x4 ws0 = {sv[7], sv[6], sv[5], sv[4]};
        f32x4 ws1 = {sv[3], sv[2], sv[1], sv[0]};
        *(f32x4*)(out + 2 * MSOFF + base) = ws0;
        *(f32x4*)(out + 2 * MSOFF + base + 4) = ws1;
      }
    }
  }
}

extern "C" void kernel_launch(void* const* d_in, const int* in_sizes, int n_in,
                              void* d_out, int out_size, void* d_ws, size_t ws_size,
                              hipStream_t stream) {
  const float* W = (const float*)d_in[0];     // (256,64,64)
  const float* bb = (const float*)d_in[1];    // (256,64)
  const float* ne = (const float*)d_in[2];    // (1,64,256)
  const float* eps0 = (const float*)d_in[3];  // (2048,64)
  const float* eps = (const float*)d_in[4];   // (255,2048,64)
  float* out = (float*)d_out;
  char* ws = (char*)d_ws;
  // workspace layout: Wf 2 MiB | Mcf 128 KiB | v 8 MiB | bnd 8 MiB (~18.2 MiB)
  bf16x8* Wf = (bf16x8*)ws;
  bf16x8* Mcf = (bf16x8*)(ws + (size_t)(2u << 20));
  float* v = (float*)(ws + (size_t)(2u << 20) + (128u << 10));
  float* bnd = (float*)(ws + (size_t)(10u << 20) + (128u << 10));

  hipLaunchKernelGGL(k_wf, dim3(256), dim3(256), 0, stream, W, Wf);
  hipLaunchKernelGGL(k_prod, dim3(15), dim3(256), 0, stream, Wf, Mcf);
  hipLaunchKernelGGL(k_phase1, dim3(15 * 128), dim3(64), 0, stream, bb, ne, eps, Wf, v);
  hipLaunchKernelGGL(k_phase2, dim3(128), dim3(64), 0, stream, eps0, Mcf, v, bnd);
  hipLaunchKernelGGL(k_phase3, dim3(16 * 128), dim3(64), 0, stream, bb, ne, eps0, eps, Wf, bnd, out);
}

// Round 2
// 903.024 us; speedup vs baseline: 1.2482x; 1.2482x over previous
//
#include <hip/hip_runtime.h>
#include <cmath>

// LinearGaussianChain v2: chunked parallel scan, fully decoupled output pack.
//  k_wf:     repack W -> bf16 B-frags; softplus table st[n][t] (t=0 -> 1.0)
//  k_prefix: per-chunk prefix matrices P_t (bf16 B-frags) for chunks 1..15
//  k_phase1: zero-start chunk chains -> x-temp (t-major fp32), chunk0 exact,
//            no in-loop barriers, eps prefetch 1 step ahead
//  k_phase2: sequential boundary stitch -> h_c (c=1..15)
//  k_fix:    x_t += P_t * h_c  (independent per (c,t,mtile); no LDS)
//  k_pack:   transpose x-temp -> (m,n,t-flipped) for x and m outputs
//  k_s:      s output from table (overwrites x-temp region last)
// x-temp lives in the s-output third of d_out (exact 134MB fit).

typedef __bf16 bf16x8 __attribute__((ext_vector_type(8)));
typedef float f32x4 __attribute__((ext_vector_type(4)));

#define XB_STRIDE 144  // bytes per LDS row: 64 bf16 + 16B pad

__device__ __forceinline__ float softplus_f(float z) {
  return (z > 20.0f) ? z : log1pf(expf(z));
}

// ---- k_wf: repack W (T,64,64) fp32 -> bf16 B-frag order; build s table ----
// Wf entry ((t*4+nt)*2+kh)*64+lane, lane=(q<<4)|n15 holds W[t][16nt+n15][32kh+8q+j]
__global__ void k_wf(const float* __restrict__ W, const float* __restrict__ ne,
                     bf16x8* __restrict__ Wf, float* __restrict__ st) {
  int t = blockIdx.x;
  for (int e = threadIdx.x; e < 512; e += blockDim.x) {
    int lane = e & 63;
    int kh = (e >> 6) & 1;
    int nt = e >> 7;
    int q = lane >> 4, n15 = lane & 15;
    int n = nt * 16 + n15;
    int k0 = kh * 32 + q * 8;
    const float* src = W + ((size_t)t * 64 + n) * 64 + k0;
    bf16x8 v;
#pragma unroll
    for (int j = 0; j < 8; ++j) v[j] = (__bf16)src[j];
    Wf[((size_t)(t * 4 + nt) * 2 + kh) * 64 + lane] = v;
  }
  if (threadIdx.x < 64) {
    int n = threadIdx.x;
    st[n * 256 + t] = (t == 0) ? 1.0f : softplus_f(ne[n * 256 + t]);
  }
}

// ---- k_prefix: chunk c=b+1, P_t = W_t * P_{t-1}, P starts at W_{16c}.
// Track Q = P^T (Q <- Q @ W_t^T), dump B-frags of P after every step. ----
__global__ __launch_bounds__(256) void k_prefix(const bf16x8* __restrict__ Wf,
                                                bf16x8* __restrict__ Pf) {
  __shared__ __align__(16) unsigned char Q[64 * XB_STRIDE];
  int b = blockIdx.x;  // 0..14, chunk c = b+1
  int c = b + 1;
  int tid = threadIdx.x;
  int lane = tid & 63, w = tid >> 6;
  int q = lane >> 4, n15 = lane & 15;
  int rbase = w * 16;
  for (int e = tid; e < 4096; e += 256) {
    int r = e >> 6, k = e & 63;
    *(__bf16*)(Q + r * XB_STRIDE + k * 2) = (__bf16)((r == k) ? 1.0f : 0.0f);
  }
  __syncthreads();
  for (int tl = 0; tl < 16; ++tl) {
    int t = c * 16 + tl;
    bf16x8 a0 = *(const bf16x8*)(Q + (rbase + n15) * XB_STRIDE + q * 16);
    bf16x8 a1 = *(const bf16x8*)(Q + (rbase + n15) * XB_STRIDE + 64 + q * 16);
    f32x4 acc[4];
#pragma unroll
    for (int nt = 0; nt < 4; ++nt) {
      bf16x8 b0 = Wf[((size_t)(t * 4 + nt) * 2 + 0) * 64 + lane];
      bf16x8 b1 = Wf[((size_t)(t * 4 + nt) * 2 + 1) * 64 + lane];
      f32x4 z = {0.f, 0.f, 0.f, 0.f};
      z = __builtin_amdgcn_mfma_f32_16x16x32_bf16(a0, b0, z, 0, 0, 0);
      z = __builtin_amdgcn_mfma_f32_16x16x32_bf16(a1, b1, z, 0, 0, 0);
      acc[nt] = z;
    }
#pragma unroll
    for (int nt = 0; nt < 4; ++nt)
#pragma unroll
      for (int reg = 0; reg < 4; ++reg)
        *(__bf16*)(Q + (rbase + 4 * q + reg) * XB_STRIDE + (nt * 16 + n15) * 2) =
            (__bf16)acc[nt][reg];
    __syncthreads();  // all rows updated before dump
    for (int e = tid; e < 512; e += 256) {
      int lane2 = e & 63;
      int kh = (e >> 6) & 1;
      int nt = e >> 7;
      int q2 = lane2 >> 4;
      int nn = nt * 16 + (lane2 & 15);
      bf16x8 v;
#pragma unroll
      for (int j = 0; j < 8; ++j)
        v[j] = *(const __bf16*)(Q + (kh * 32 + q2 * 8 + j) * XB_STRIDE + nn * 2);
      Pf[((size_t)(b * 16 + tl) * 8 + nt * 2 + kh) * 64 + lane2] = v;
    }
    __syncthreads();  // dump done before next overwrite
  }
}

// ---- k_phase1: zero-start chunk chains, x-temp t-major. 4 indep waves/block.
__global__ __launch_bounds__(256) void k_phase1(
    const float* __restrict__ bb, const float* __restrict__ st,
    const float* __restrict__ eps0, const float* __restrict__ eps,
    const bf16x8* __restrict__ Wf, float* __restrict__ xtemp) {
  __shared__ float stab[16][64];
  __shared__ float btab[16][64];
  __shared__ __align__(16) unsigned char xball[4 * 16 * XB_STRIDE];
  int tid = threadIdx.x, w = tid >> 6, lane = tid & 63;
  unsigned char* xb = xball + w * 16 * XB_STRIDE;
  int c = blockIdx.x >> 5;                     // 0..15
  int r0 = ((blockIdx.x & 31) * 4 + w) * 16;   // 16-row tile
  int q = lane >> 4, n15 = lane & 15;
  for (int e = tid; e < 1024; e += 256) {
    int tl = e >> 6, n = e & 63, t = c * 16 + tl;
    stab[tl][n] = st[n * 256 + t];
    btab[tl][n] = bb[t * 64 + n];
  }
  if (c == 0) {
    for (int i = 0; i < 16; ++i) {
      float v = eps0[(size_t)(r0 + i) * 64 + lane];
      *(__bf16*)(xb + i * XB_STRIDE + lane * 2) = (__bf16)v;
      xtemp[((size_t)(r0 + i)) * 64 + lane] = v;  // t=0
    }
  } else {
    for (int i = 0; i < 16; ++i)
      *(__bf16*)(xb + i * XB_STRIDE + lane * 2) = (__bf16)0.0f;
  }
  __syncthreads();  // stab/btab ready
  int t0 = (c == 0) ? 1 : c * 16;
  int t1 = c * 16 + 15;
  float epc[16], epn[16];
#pragma unroll
  for (int nt = 0; nt < 4; ++nt)
#pragma unroll
    for (int reg = 0; reg < 4; ++reg)
      epc[nt * 4 + reg] =
          eps[((size_t)(t0 - 1) * 2048 + r0 + 4 * q + reg) * 64 + nt * 16 + n15];
  for (int t = t0; t <= t1; ++t) {
    bool more = (t < t1);
    if (more) {
#pragma unroll
      for (int nt = 0; nt < 4; ++nt)
#pragma unroll
        for (int reg = 0; reg < 4; ++reg)
          epn[nt * 4 + reg] =
              eps[((size_t)t * 2048 + r0 + 4 * q + reg) * 64 + nt * 16 + n15];
    }
    bf16x8 a0 = *(const bf16x8*)(xb + n15 * XB_STRIDE + q * 16);
    bf16x8 a1 = *(const bf16x8*)(xb + n15 * XB_STRIDE + 64 + q * 16);
    f32x4 acc[4];
#pragma unroll
    for (int nt = 0; nt < 4; ++nt) {
      bf16x8 b0 = Wf[((size_t)(t * 4 + nt) * 2 + 0) * 64 + lane];
      bf16x8 b1 = Wf[((size_t)(t * 4 + nt) * 2 + 1) * 64 + lane];
      f32x4 z = {0.f, 0.f, 0.f, 0.f};
      z = __builtin_amdgcn_mfma_f32_16x16x32_bf16(a0, b0, z, 0, 0, 0);
      z = __builtin_amdgcn_mfma_f32_16x16x32_bf16(a1, b1, z, 0, 0, 0);
      acc[nt] = z;
    }
    int tl = t - c * 16;
#pragma unroll
    for (int nt = 0; nt < 4; ++nt) {
      int n = nt * 16 + n15;
      float sv = stab[tl][n];
      float bv = btab[tl][n];
#pragma unroll
      for (int reg = 0; reg < 4; ++reg) {
        int row = 4 * q + reg;
        float xn = acc[nt][reg] + bv + sv * epc[nt * 4 + reg];
        xtemp[((size_t)t * 2048 + r0 + row) * 64 + n] = xn;
        *(__bf16*)(xb + row * XB_STRIDE + n * 2) = (__bf16)xn;
      }
    }
    if (more) {
#pragma unroll
      for (int i = 0; i < 16; ++i) epc[i] = epn[i];
    }
  }
}

// ---- k_phase2: h_1 = x_15; h_{c+1} = tail_c + M_c h_c (M_c = P at chunk end)
__global__ __launch_bounds__(256) void k_phase2(const bf16x8* __restrict__ Pf,
                                                const float* __restrict__ xtemp,
                                                float* __restrict__ h) {
  __shared__ __align__(16) unsigned char hball[4 * 16 * XB_STRIDE];
  int tid = threadIdx.x, w = tid >> 6, lane = tid & 63;
  unsigned char* hb = hball + w * 16 * XB_STRIDE;
  int r0 = (blockIdx.x * 4 + w) * 16;
  int q = lane >> 4, n15 = lane & 15;
  for (int i = 0; i < 16; ++i) {
    float v = xtemp[((size_t)15 * 2048 + r0 + i) * 64 + lane];
    *(__bf16*)(hb + i * XB_STRIDE + lane * 2) = (__bf16)v;
    h[((size_t)1 * 2048 + r0 + i) * 64 + lane] = v;
  }
  for (int c = 1; c <= 14; ++c) {
    bf16x8 a0 = *(const bf16x8*)(hb + n15 * XB_STRIDE + q * 16);
    bf16x8 a1 = *(const bf16x8*)(hb + n15 * XB_STRIDE + 64 + q * 16);
    f32x4 acc[4];
#pragma unroll
    for (int nt = 0; nt < 4; ++nt) {
      bf16x8 b0 = Pf[((size_t)((c - 1) * 16 + 15) * 8 + nt * 2 + 0) * 64 + lane];
      bf16x8 b1 = Pf[((size_t)((c - 1) * 16 + 15) * 8 + nt * 2 + 1) * 64 + lane];
      f32x4 z = {0.f, 0.f, 0.f, 0.f};
      z = __builtin_amdgcn_mfma_f32_16x16x32_bf16(a0, b0, z, 0, 0, 0);
      z = __builtin_amdgcn_mfma_f32_16x16x32_bf16(a1, b1, z, 0, 0, 0);
      acc[nt] = z;
    }
#pragma unroll
    for (int nt = 0; nt < 4; ++nt) {
      int n = nt * 16 + n15;
#pragma unroll
      for (int reg = 0; reg < 4; ++reg) {
        int row = 4 * q + reg;
        float tail = xtemp[((size_t)(16 * c + 15) * 2048 + r0 + row) * 64 + n];
        float hn = acc[nt][reg] + tail;
        h[((size_t)(c + 1) * 2048 + r0 + row) * 64 + n] = hn;
        *(__bf16*)(hb + row * XB_STRIDE + n * 2) = (__bf16)hn;
      }
    }
  }
}

// ---- k_fix: x_t += P_t * h_c, independent per (c,t,mtile). No LDS. ----
__global__ __launch_bounds__(256) void k_fix(const bf16x8* __restrict__ Pf,
                                             const float* __restrict__ h,
                                             float* __restrict__ xtemp) {
  int tid = threadIdx.x, w = tid >> 6, lane = tid & 63;
  int r0 = (blockIdx.x & 31) * 64 + w * 16;
  int ct = blockIdx.x >> 5;  // 0..239
  int c1 = ct >> 4;
  int tl = ct & 15;
  int c = c1 + 1;
  int t = 16 * c + tl;
  int q = lane >> 4, n15 = lane & 15;
  const float* hrow = h + ((size_t)c * 2048 + r0 + n15) * 64;
  bf16x8 a0, a1;
#pragma unroll
  for (int j = 0; j < 8; ++j) {
    a0[j] = (__bf16)hrow[8 * q + j];
    a1[j] = (__bf16)hrow[32 + 8 * q + j];
  }
#pragma unroll
  for (int nt = 0; nt < 4; ++nt) {
    bf16x8 b0 = Pf[((size_t)(c1 * 16 + tl) * 8 + nt * 2 + 0) * 64 + lane];
    bf16x8 b1 = Pf[((size_t)(c1 * 16 + tl) * 8 + nt * 2 + 1) * 64 + lane];
    f32x4 z = {0.f, 0.f, 0.f, 0.f};
    z = __builtin_amdgcn_mfma_f32_16x16x32_bf16(a0, b0, z, 0, 0, 0);
    z = __builtin_amdgcn_mfma_f32_16x16x32_bf16(a1, b1, z, 0, 0, 0);
#pragma unroll
    for (int reg = 0; reg < 4; ++reg) {
      size_t idx = ((size_t)t * 2048 + r0 + 4 * q + reg) * 64 + nt * 16 + n15;
      xtemp[idx] += z[reg];
    }
  }
}

// ---- k_pack: (t,m,n) -> (m,n,255-t) for x and m outputs, LDS transpose ----
__global__ __launch_bounds__(256) void k_pack(const float* __restrict__ st,
                                              const float* __restrict__ eps0,
                                              const float* __restrict__ eps,
                                              const float* __restrict__ xtemp,
                                              float* __restrict__ out) {
  __shared__ float ss[64][65];
  __shared__ float xs[64][65];
  __shared__ float es[64][65];
  int tid = threadIdx.x;
  int mt = blockIdx.x >> 2;   // 0..255 -> m0 = mt*8
  int tt = blockIdx.x & 3;    // t tile
  int tt0 = tt * 64;
  int m0 = mt * 8;
  {
    int n = tid >> 2, tc = tid & 3;
#pragma unroll
    for (int k = 0; k < 4; ++k) {
      int t4 = tc * 16 + k * 4;
      const float4 sv = *(const float4*)(st + n * 256 + tt0 + t4);
      ss[t4 + 0][n] = sv.x;
      ss[t4 + 1][n] = sv.y;
      ss[t4 + 2][n] = sv.z;
      ss[t4 + 3][n] = sv.w;
    }
  }
  const size_t MSOFF = (size_t)2048 * 64 * 256;
  for (int mi = 0; mi < 8; ++mi) {
    int mm = m0 + mi;
    __syncthreads();  // ss ready (mi=0) / previous write phase done
    {
      int n = tid & 63, dt = tid >> 6;
#pragma unroll
      for (int i = 0; i < 16; ++i) {
        int tl = i * 4 + dt;
        int t = tt0 + tl;
        xs[tl][n] = xtemp[((size_t)t * 2048 + mm) * 64 + n];
        es[tl][n] = (t == 0) ? eps0[(size_t)mm * 64 + n]
                             : eps[((size_t)(t - 1) * 2048 + mm) * 64 + n];
      }
    }
    __syncthreads();
    {
      int n = tid >> 2, tc = tid & 3;
      size_t obase = ((size_t)mm * 64 + n) * 256;
#pragma unroll
      for (int k = 0; k < 4; ++k) {
        int tlh = tc * 16 + 4 * k + 3;
        int base_i = 255 - tt0 - tlh;
        f32x4 xv, mv;
#pragma unroll
        for (int j = 0; j < 4; ++j) {
          int tl = tlh - j;
          float x = xs[tl][n];
          float s = ss[tl][n];
          float e = es[tl][n];
          xv[j] = x;
          mv[j] = x - s * e;
        }
        *(f32x4*)(out + obase + base_i) = xv;
        *(f32x4*)(out + MSOFF + obase + base_i) = mv;
      }
    }
  }
}

// ---- k_s: s output = table broadcast over m, t-flipped ----
__global__ __launch_bounds__(256) void k_s(const float* __restrict__ st,
                                           float* __restrict__ out) {
  int gid = blockIdx.x * 256 + threadIdx.x;  // 0..8388607
  int i0 = (gid & 63) * 4;
  int n = (gid >> 6) & 63;
  int m = gid >> 12;
  const float4 rv = *(const float4*)(st + n * 256 + 252 - i0);
  f32x4 v = {rv.w, rv.z, rv.y, rv.x};
  *(f32x4*)(out + (size_t)2 * 2048 * 64 * 256 + ((size_t)m * 64 + n) * 256 + i0) = v;
}

extern "C" void kernel_launch(void* const* d_in, const int* in_sizes, int n_in,
                              void* d_out, int out_size, void* d_ws, size_t ws_size,
                              hipStream_t stream) {
  const float* W = (const float*)d_in[0];     // (256,64,64)
  const float* bb = (const float*)d_in[1];    // (256,64)
  const float* ne = (const float*)d_in[2];    // (1,64,256)
  const float* eps0 = (const float*)d_in[3];  // (2048,64)
  const float* eps = (const float*)d_in[4];   // (255,2048,64)
  float* out = (float*)d_out;
  char* ws = (char*)d_ws;
  // ws layout: Wf 2MB | st 256KB | Pf 2MB | h 8MB  (~12.3 MB)
  bf16x8* Wf = (bf16x8*)ws;
  float* st = (float*)(ws + (size_t)(2u << 20));
  bf16x8* Pf = (bf16x8*)(ws + (size_t)(2u << 20) + (256u << 10));
  float* h = (float*)(ws + (size_t)(4u << 20) + (256u << 10));
  // x-temp (t-major, 134MB) lives in the s-output third of d_out.
  float* xtemp = out + (size_t)2 * 2048 * 64 * 256;

  hipLaunchKernelGGL(k_wf, dim3(256), dim3(256), 0, stream, W, ne, Wf, st);
  hipLaunchKernelGGL(k_prefix, dim3(15), dim3(256), 0, stream, Wf, Pf);
  hipLaunchKernelGGL(k_phase1, dim3(512), dim3(256), 0, stream, bb, st, eps0, eps, Wf, xtemp);
  hipLaunchKernelGGL(k_phase2, dim3(32), dim3(256), 0, stream, Pf, xtemp, h);
  hipLaunchKernelGGL(k_fix, dim3(7680), dim3(256), 0, stream, Pf, h, xtemp);
  hipLaunchKernelGGL(k_pack, dim3(1024), dim3(256), 0, stream, st, eps0, eps, xtemp, out);
  hipLaunchKernelGGL(k_s, dim3(32768), dim3(256), 0, stream, st, out);
}